// Round 3
// baseline (603.519 us; speedup 1.0000x reference)
//
#include <hip/hip_runtime.h>
#include <hip/hip_bf16.h>
#include <cstdint>

// Problem constants
#define NB    524288      // batch rows
#define NDIN  32
#define NH    128
#define NLD   16
#define NNE   512

// d_out element offsets (float32 elements)
#define OFF_ZQ   0
#define OFF_SC   8388608
#define OFF_RS   8912896
#define OFF_LOSS 9437184
#define OFF_IDS  9437185

// d_ws float layout
#define WS_LOSS 0
#define WS_W1D  64
#define WS_W1S  (64 + 4096)
#define WS_W1R  (64 + 8192)
#define WS_CBT  (64 + 12288)
#define WS_C2   (64 + 12288 + 8192)

// ---------------------------------------------------------------------------
// Prep: transpose W1 matrices (32x128 -> 128x32), codebook (16x512 -> 512x16),
// precompute ||c_j||^2 with numpy's pairwise (8-accumulator) order over n=16,
// zero loss accumulator.
// ---------------------------------------------------------------------------
__global__ __launch_bounds__(256) void prep_kernel(
    const float* __restrict__ cb,
    const float* __restrict__ w1d, const float* __restrict__ w1s,
    const float* __restrict__ w1r, float* __restrict__ ws)
{
    int gid = blockIdx.x * 256 + threadIdx.x;
    if (gid == 0) ws[WS_LOSS] = 0.0f;
    if (gid < 4096) {
        int j = gid >> 5, k = gid & 31;           // dest [j][k] <- src [k][j]
        ws[WS_W1D + gid] = w1d[k * NH + j];
        ws[WS_W1S + gid] = w1s[k * NH + j];
        ws[WS_W1R + gid] = w1r[k * NH + j];
    } else if (gid < 4096 + 8192) {
        int idx = gid - 4096;
        int j = idx >> 4, k = idx & 15;           // cbT[j][k] = cb[k][j]
        ws[WS_CBT + idx] = cb[k * NNE + j];
    } else if (gid < 4096 + 8192 + 512) {
        int j = gid - (4096 + 8192);
        // numpy: tmp = cb*cb (each rounded), then add.reduce axis 0 pairwise:
        // r[m] = t[m] + t[m+8]; ((r0+r1)+(r2+r3)) + ((r4+r5)+(r6+r7))
        float t[16];
#pragma unroll
        for (int k = 0; k < 16; ++k) {
            float c = cb[k * NNE + j];
            t[k] = __fmul_rn(c, c);
        }
        float r8[8];
#pragma unroll
        for (int m = 0; m < 8; ++m) r8[m] = __fadd_rn(t[m], t[m + 8]);
        float acc = __fadd_rn(
            __fadd_rn(__fadd_rn(r8[0], r8[1]), __fadd_rn(r8[2], r8[3])),
            __fadd_rn(__fadd_rn(r8[4], r8[5]), __fadd_rn(r8[6], r8[7])));
        ws[WS_C2 + j] = acc;
    }
}

// ---------------------------------------------------------------------------
// Main: one thread per row. Weight/codebook accesses are wave-uniform ->
// scalar (s_load) path. __launch_bounds__(256,4) = 128-VGPR budget so the
// row (x[32]) and zd[16] stay register-resident (r2 showed a 32-VGPR
// allocation with ~2x VALU bloat from spill/remat).
// ---------------------------------------------------------------------------
__global__ __launch_bounds__(256, 4) void main_kernel(
    const float* __restrict__ z,
    const float* __restrict__ b1d, const float* __restrict__ w2d, const float* __restrict__ b2d,
    const float* __restrict__ b1s, const float* __restrict__ w2s, const float* __restrict__ b2s,
    const float* __restrict__ b1r, const float* __restrict__ w2r, const float* __restrict__ b2r,
    const float* __restrict__ ws,
    float* __restrict__ loss_acc,
    float* __restrict__ out)
{
    const int i = blockIdx.x * 256 + threadIdx.x;

    const float* __restrict__ w1dT = ws + WS_W1D;
    const float* __restrict__ w1sT = ws + WS_W1S;
    const float* __restrict__ w1rT = ws + WS_W1R;
    const float* __restrict__ cbT  = ws + WS_CBT;
    const float* __restrict__ c2   = ws + WS_C2;

    // load row (32 floats, 8x float4) -> registers
    float x[32];
    const float4* zv = reinterpret_cast<const float4*>(z) + (size_t)i * 8;
#pragma unroll
    for (int m = 0; m < 8; ++m) {
        float4 v = zv[m];
        x[4*m+0] = v.x; x[4*m+1] = v.y; x[4*m+2] = v.z; x[4*m+3] = v.w;
    }

    float zd[16];
#pragma unroll
    for (int l = 0; l < 16; ++l) zd[l] = 0.0f;
    float sacc = 0.0f, racc = 0.0f;

    // fused first+second layers of the three MLPs, hidden unit j at a time.
#pragma unroll 2
    for (int j = 0; j < NH; ++j) {
        float hd = 0.0f, hs = 0.0f, hr = 0.0f;
        const float* wd = w1dT + j * 32;
        const float* wsr = w1sT + j * 32;
        const float* wr = w1rT + j * 32;
#pragma unroll
        for (int k = 0; k < 32; ++k) {
            hd = __fmaf_rn(x[k], wd[k], hd);
            hs = __fmaf_rn(x[k], wsr[k], hs);
            hr = __fmaf_rn(x[k], wr[k], hr);
        }
        hd = fmaxf(__fadd_rn(hd, b1d[j]), 0.0f);
        hs = fmaxf(__fadd_rn(hs, b1s[j]), 0.0f);
        hr = fmaxf(__fadd_rn(hr, b1r[j]), 0.0f);
        const float* w2row = w2d + j * 16;
#pragma unroll
        for (int l = 0; l < 16; ++l) zd[l] = __fmaf_rn(hd, w2row[l], zd[l]);
        sacc = __fmaf_rn(hs, w2s[j], sacc);
        racc = __fmaf_rn(hr, w2r[j], racc);
    }
#pragma unroll
    for (int l = 0; l < 16; ++l) zd[l] = __fadd_rn(zd[l], b2d[l]);

    float scaler   = __fadd_rn(sacc, b2s[0]);
    float redshift = fmaxf(__fadd_rn(racc, b2r[0]), 0.0f);

    // s = np.sum(zf*zf, axis=1): numpy pairwise, 8 accumulators + tree (inline)
    float s;
    {
        float r0 = __fadd_rn(__fmul_rn(zd[0],  zd[0]),  __fmul_rn(zd[8],  zd[8]));
        float r1 = __fadd_rn(__fmul_rn(zd[1],  zd[1]),  __fmul_rn(zd[9],  zd[9]));
        float r2 = __fadd_rn(__fmul_rn(zd[2],  zd[2]),  __fmul_rn(zd[10], zd[10]));
        float r3 = __fadd_rn(__fmul_rn(zd[3],  zd[3]),  __fmul_rn(zd[11], zd[11]));
        float r4 = __fadd_rn(__fmul_rn(zd[4],  zd[4]),  __fmul_rn(zd[12], zd[12]));
        float r5 = __fadd_rn(__fmul_rn(zd[5],  zd[5]),  __fmul_rn(zd[13], zd[13]));
        float r6 = __fadd_rn(__fmul_rn(zd[6],  zd[6]),  __fmul_rn(zd[14], zd[14]));
        float r7 = __fadd_rn(__fmul_rn(zd[7],  zd[7]),  __fmul_rn(zd[15], zd[15]));
        s = __fadd_rn(__fadd_rn(__fadd_rn(r0, r1), __fadd_rn(r2, r3)),
                      __fadd_rn(__fadd_rn(r4, r5), __fadd_rn(r6, r7)));
    }

    // VQ argmin: d_j = (s - 2*(zf.c_j)) + ||c_j||^2, first-index tie-break
    float best = 3.4028235e38f;
    int bid = 0;
#pragma unroll 4
    for (int j = 0; j < NNE; ++j) {
        const float* cj = cbT + j * 16;
        float b = __fmul_rn(zd[0], cj[0]);
#pragma unroll
        for (int k = 1; k < 16; ++k) b = __fmaf_rn(zd[k], cj[k], b);
        float dj = __fadd_rn(__fsub_rn(s, __fmul_rn(2.0f, b)), c2[j]);
        bool t = dj < best;
        best = t ? dj : best;
        bid  = t ? j : bid;
    }

    // gather z_q, z_q_st = zd + (z_q - zd) in f32, loss partial, store inline
    float lsum = 0.0f;
    float4* ozq = reinterpret_cast<float4*>(out) + (size_t)i * 4;
    const float* cq = cbT + bid * 16;
#pragma unroll
    for (int m = 0; m < 4; ++m) {
        float d0 = __fsub_rn(cq[4*m+0], zd[4*m+0]);
        float d1 = __fsub_rn(cq[4*m+1], zd[4*m+1]);
        float d2 = __fsub_rn(cq[4*m+2], zd[4*m+2]);
        float d3 = __fsub_rn(cq[4*m+3], zd[4*m+3]);
        lsum = __fmaf_rn(d0, d0, lsum);
        lsum = __fmaf_rn(d1, d1, lsum);
        lsum = __fmaf_rn(d2, d2, lsum);
        lsum = __fmaf_rn(d3, d3, lsum);
        ozq[m] = make_float4(__fadd_rn(zd[4*m+0], d0), __fadd_rn(zd[4*m+1], d1),
                             __fadd_rn(zd[4*m+2], d2), __fadd_rn(zd[4*m+3], d3));
    }

    out[OFF_SC  + i] = scaler;
    out[OFF_RS  + i] = redshift;
    out[OFF_IDS + i] = (float)bid;

    // loss reduction: wave shuffle -> LDS -> one atomic per block
#pragma unroll
    for (int off = 32; off > 0; off >>= 1) lsum += __shfl_down(lsum, off);
    __shared__ float red[4];
    if ((threadIdx.x & 63) == 0) red[threadIdx.x >> 6] = lsum;
    __syncthreads();
    if (threadIdx.x == 0)
        atomicAdd(loss_acc, red[0] + red[1] + red[2] + red[3]);
}

__global__ void fin_kernel(const float* __restrict__ ws, float* __restrict__ out) {
    float m = ws[WS_LOSS] / 8388608.0f;   // mean over B*LD
    out[OFF_LOSS] = m + 0.25f * m;        // (1 + BETA) * mean
}

extern "C" void kernel_launch(void* const* d_in, const int* in_sizes, int n_in,
                              void* d_out, int out_size, void* d_ws, size_t ws_size,
                              hipStream_t stream)
{
    const float* z      = (const float*)d_in[0];
    const float* cb     = (const float*)d_in[1];
    const float* dec_w1 = (const float*)d_in[2];
    const float* dec_b1 = (const float*)d_in[3];
    const float* dec_w2 = (const float*)d_in[4];
    const float* dec_b2 = (const float*)d_in[5];
    const float* sc_w1  = (const float*)d_in[6];
    const float* sc_b1  = (const float*)d_in[7];
    const float* sc_w2  = (const float*)d_in[8];
    const float* sc_b2  = (const float*)d_in[9];
    const float* rs_w1  = (const float*)d_in[10];
    const float* rs_b1  = (const float*)d_in[11];
    const float* rs_w2  = (const float*)d_in[12];
    const float* rs_b2  = (const float*)d_in[13];

    float* ws = (float*)d_ws;
    float* out = (float*)d_out;

    prep_kernel<<<50, 256, 0, stream>>>(cb, dec_w1, sc_w1, rs_w1, ws);
    main_kernel<<<NB / 256, 256, 0, stream>>>(
        z,
        dec_b1, dec_w2, dec_b2,
        sc_b1,  sc_w2,  sc_b2,
        rs_b1,  rs_w2,  rs_b2,
        ws, ws + WS_LOSS, out);
    fin_kernel<<<1, 1, 0, stream>>>(ws, out);
}

// Round 4
// 401.417 us; speedup vs baseline: 1.5035x; 1.5035x over previous
//
#include <hip/hip_runtime.h>
#include <hip/hip_bf16.h>
#include <cstdint>

// Problem constants
#define NB    524288      // batch rows
#define NDIN  32
#define NH    128
#define NLD   16
#define NNE   512

// d_out element offsets (float32 elements)
#define OFF_ZQ   0
#define OFF_SC   8388608
#define OFF_RS   8912896
#define OFF_LOSS 9437184
#define OFF_IDS  9437185

// d_ws float layout
#define WS_LOSS 0
#define WS_W1D  64
#define WS_W1S  (64 + 4096)
#define WS_W1R  (64 + 8192)
#define WS_CBT  (64 + 12288)
#define WS_C2   (64 + 12288 + 8192)

typedef float v2f __attribute__((ext_vector_type(2)));

static __device__ __forceinline__ v2f mk2(float a, float b) { v2f r; r[0] = a; r[1] = b; return r; }
static __device__ __forceinline__ v2f bc2(float s) { return mk2(s, s); }
static __device__ __forceinline__ v2f vfma2(v2f a, v2f b, v2f c) { return __builtin_elementwise_fma(a, b, c); }
static __device__ __forceinline__ v2f vmax0(v2f a) { return __builtin_elementwise_max(a, mk2(0.0f, 0.0f)); }

// ---------------------------------------------------------------------------
// Prep: transpose W1 matrices (32x128 -> 128x32), codebook (16x512 -> 512x16),
// precompute ||c_j||^2 with numpy's pairwise (8-accumulator) order over n=16,
// zero loss accumulator.
// ---------------------------------------------------------------------------
__global__ __launch_bounds__(256) void prep_kernel(
    const float* __restrict__ cb,
    const float* __restrict__ w1d, const float* __restrict__ w1s,
    const float* __restrict__ w1r, float* __restrict__ ws)
{
    int gid = blockIdx.x * 256 + threadIdx.x;
    if (gid == 0) ws[WS_LOSS] = 0.0f;
    if (gid < 4096) {
        int j = gid >> 5, k = gid & 31;           // dest [j][k] <- src [k][j]
        ws[WS_W1D + gid] = w1d[k * NH + j];
        ws[WS_W1S + gid] = w1s[k * NH + j];
        ws[WS_W1R + gid] = w1r[k * NH + j];
    } else if (gid < 4096 + 8192) {
        int idx = gid - 4096;
        int j = idx >> 4, k = idx & 15;           // cbT[j][k] = cb[k][j]
        ws[WS_CBT + idx] = cb[k * NNE + j];
    } else if (gid < 4096 + 8192 + 512) {
        int j = gid - (4096 + 8192);
        float t[16];
#pragma unroll
        for (int k = 0; k < 16; ++k) {
            float c = cb[k * NNE + j];
            t[k] = __fmul_rn(c, c);
        }
        float r8[8];
#pragma unroll
        for (int m = 0; m < 8; ++m) r8[m] = __fadd_rn(t[m], t[m + 8]);
        float acc = __fadd_rn(
            __fadd_rn(__fadd_rn(r8[0], r8[1]), __fadd_rn(r8[2], r8[3])),
            __fadd_rn(__fadd_rn(r8[4], r8[5]), __fadd_rn(r8[6], r8[7])));
        ws[WS_C2 + j] = acc;
    }
}

// ---------------------------------------------------------------------------
// Main: one thread per TWO rows, packed across rows as v2f so the fp32 math
// runs on v_pk_fma_f32 (2x fp32 rate; MI355X's 157 TF is the packed rate) and
// every uniform weight/codebook load feeds 2 FMAs instead of 1. Per-row
// accumulation order is bit-identical to the round-2 passing kernel (each row
// occupies one half of the pair; sequential-k FMA chains preserved).
// ---------------------------------------------------------------------------
__global__ __launch_bounds__(256, 4) void main_kernel(
    const float* __restrict__ z,
    const float* __restrict__ b1d, const float* __restrict__ w2d, const float* __restrict__ b2d,
    const float* __restrict__ b1s, const float* __restrict__ w2s, const float* __restrict__ b2s,
    const float* __restrict__ b1r, const float* __restrict__ w2r, const float* __restrict__ b2r,
    const float* __restrict__ ws,
    float* __restrict__ loss_acc,
    float* __restrict__ out)
{
#pragma clang fp contract(off)
    const int i  = blockIdx.x * 256 + threadIdx.x;   // pair index
    const int r0 = 2 * i;                            // rows r0, r0+1

    const float* __restrict__ w1dT = ws + WS_W1D;
    const float* __restrict__ w1sT = ws + WS_W1S;
    const float* __restrict__ w1rT = ws + WS_W1R;
    const float* __restrict__ cbT  = ws + WS_CBT;
    const float* __restrict__ c2   = ws + WS_C2;

    // load both rows (2 x 32 floats) and pack across rows
    v2f x2[32];
    {
        const float4* zv = reinterpret_cast<const float4*>(z) + (size_t)r0 * 8;
#pragma unroll
        for (int m = 0; m < 8; ++m) {
            float4 a = zv[m];       // row r0
            float4 b = zv[m + 8];   // row r0+1
            x2[4*m+0] = mk2(a.x, b.x);
            x2[4*m+1] = mk2(a.y, b.y);
            x2[4*m+2] = mk2(a.z, b.z);
            x2[4*m+3] = mk2(a.w, b.w);
        }
    }

    v2f zd2[16];
#pragma unroll
    for (int l = 0; l < 16; ++l) zd2[l] = mk2(0.0f, 0.0f);
    v2f sacc2 = mk2(0.0f, 0.0f), racc2 = mk2(0.0f, 0.0f);

    for (int j = 0; j < NH; ++j) {
        v2f hd2 = mk2(0.0f, 0.0f), hs2 = mk2(0.0f, 0.0f), hr2 = mk2(0.0f, 0.0f);
        const float* wd  = w1dT + j * 32;
        const float* wsr = w1sT + j * 32;
        const float* wr  = w1rT + j * 32;
#pragma unroll
        for (int k = 0; k < 32; ++k) {
            hd2 = vfma2(x2[k], bc2(wd[k]),  hd2);
            hs2 = vfma2(x2[k], bc2(wsr[k]), hs2);
            hr2 = vfma2(x2[k], bc2(wr[k]),  hr2);
        }
        hd2 = vmax0(hd2 + bc2(b1d[j]));
        hs2 = vmax0(hs2 + bc2(b1s[j]));
        hr2 = vmax0(hr2 + bc2(b1r[j]));
        const float* w2row = w2d + j * 16;
#pragma unroll
        for (int l = 0; l < 16; ++l) zd2[l] = vfma2(hd2, bc2(w2row[l]), zd2[l]);
        sacc2 = vfma2(hs2, bc2(w2s[j]), sacc2);
        racc2 = vfma2(hr2, bc2(w2r[j]), racc2);
    }
#pragma unroll
    for (int l = 0; l < 16; ++l) zd2[l] = zd2[l] + bc2(b2d[l]);

    v2f scaler2   = sacc2 + bc2(b2s[0]);
    v2f redshift2 = vmax0(racc2 + bc2(b2r[0]));

    // s = sum(zf*zf): numpy pairwise (8 accumulators + tree), per-row exact
    v2f s2;
    {
        v2f q0 = zd2[0]  * zd2[0],  q8  = zd2[8]  * zd2[8];
        v2f q1 = zd2[1]  * zd2[1],  q9  = zd2[9]  * zd2[9];
        v2f q2 = zd2[2]  * zd2[2],  q10 = zd2[10] * zd2[10];
        v2f q3 = zd2[3]  * zd2[3],  q11 = zd2[11] * zd2[11];
        v2f q4 = zd2[4]  * zd2[4],  q12 = zd2[12] * zd2[12];
        v2f q5 = zd2[5]  * zd2[5],  q13 = zd2[13] * zd2[13];
        v2f q6 = zd2[6]  * zd2[6],  q14 = zd2[14] * zd2[14];
        v2f q7 = zd2[7]  * zd2[7],  q15 = zd2[15] * zd2[15];
        v2f r0v = q0 + q8,  r1v = q1 + q9,  r2v = q2 + q10, r3v = q3 + q11;
        v2f r4v = q4 + q12, r5v = q5 + q13, r6v = q6 + q14, r7v = q7 + q15;
        s2 = ((r0v + r1v) + (r2v + r3v)) + ((r4v + r5v) + (r6v + r7v));
    }

    // VQ argmin over 512 entries; codebook row broadcast feeds both rows
    float best0 = 3.4028235e38f, best1 = 3.4028235e38f;
    int bid0 = 0, bid1 = 0;
#pragma unroll 2
    for (int j = 0; j < NNE; ++j) {
        const float* cj = cbT + j * 16;
        v2f b2 = zd2[0] * bc2(cj[0]);
#pragma unroll
        for (int k = 1; k < 16; ++k) b2 = vfma2(zd2[k], bc2(cj[k]), b2);
        v2f dj2 = (s2 - bc2(2.0f) * b2) + bc2(c2[j]);   // 2*b exact; sub+add round like ref
        float d0 = dj2[0], d1 = dj2[1];
        bool t0 = d0 < best0; best0 = t0 ? d0 : best0; bid0 = t0 ? j : bid0;
        bool t1 = d1 < best1; best1 = t1 ? d1 : best1; bid1 = t1 ? j : bid1;
    }

    // gather z_q, z_q_st = zd + (q - zd), loss partials, stores
    float lsum = 0.0f;
    float4* ozq = reinterpret_cast<float4*>(out) + (size_t)r0 * 4;
    {
        const float4* cq = reinterpret_cast<const float4*>(cbT + bid0 * 16);
#pragma unroll
        for (int m = 0; m < 4; ++m) {
            float4 q = cq[m];
            float z0v = zd2[4*m+0][0], z1v = zd2[4*m+1][0], z2v = zd2[4*m+2][0], z3v = zd2[4*m+3][0];
            float e0 = __fsub_rn(q.x, z0v), e1 = __fsub_rn(q.y, z1v);
            float e2 = __fsub_rn(q.z, z2v), e3 = __fsub_rn(q.w, z3v);
            lsum = __fmaf_rn(e0, e0, lsum); lsum = __fmaf_rn(e1, e1, lsum);
            lsum = __fmaf_rn(e2, e2, lsum); lsum = __fmaf_rn(e3, e3, lsum);
            ozq[m] = make_float4(__fadd_rn(z0v, e0), __fadd_rn(z1v, e1),
                                 __fadd_rn(z2v, e2), __fadd_rn(z3v, e3));
        }
    }
    {
        const float4* cq = reinterpret_cast<const float4*>(cbT + bid1 * 16);
#pragma unroll
        for (int m = 0; m < 4; ++m) {
            float4 q = cq[m];
            float z0v = zd2[4*m+0][1], z1v = zd2[4*m+1][1], z2v = zd2[4*m+2][1], z3v = zd2[4*m+3][1];
            float e0 = __fsub_rn(q.x, z0v), e1 = __fsub_rn(q.y, z1v);
            float e2 = __fsub_rn(q.z, z2v), e3 = __fsub_rn(q.w, z3v);
            lsum = __fmaf_rn(e0, e0, lsum); lsum = __fmaf_rn(e1, e1, lsum);
            lsum = __fmaf_rn(e2, e2, lsum); lsum = __fmaf_rn(e3, e3, lsum);
            ozq[4 + m] = make_float4(__fadd_rn(z0v, e0), __fadd_rn(z1v, e1),
                                     __fadd_rn(z2v, e2), __fadd_rn(z3v, e3));
        }
    }

    *reinterpret_cast<float2*>(out + OFF_SC  + r0) = make_float2(scaler2[0],   scaler2[1]);
    *reinterpret_cast<float2*>(out + OFF_RS  + r0) = make_float2(redshift2[0], redshift2[1]);
    *reinterpret_cast<float2*>(out + OFF_IDS + r0) = make_float2((float)bid0,  (float)bid1);

    // loss reduction: wave shuffle -> LDS -> one atomic per block
#pragma unroll
    for (int off = 32; off > 0; off >>= 1) lsum += __shfl_down(lsum, off);
    __shared__ float red[4];
    if ((threadIdx.x & 63) == 0) red[threadIdx.x >> 6] = lsum;
    __syncthreads();
    if (threadIdx.x == 0)
        atomicAdd(loss_acc, red[0] + red[1] + red[2] + red[3]);
}

__global__ void fin_kernel(const float* __restrict__ ws, float* __restrict__ out) {
    float m = ws[WS_LOSS] / 8388608.0f;   // mean over B*LD
    out[OFF_LOSS] = m + 0.25f * m;        // (1 + BETA) * mean
}

extern "C" void kernel_launch(void* const* d_in, const int* in_sizes, int n_in,
                              void* d_out, int out_size, void* d_ws, size_t ws_size,
                              hipStream_t stream)
{
    const float* z      = (const float*)d_in[0];
    const float* cb     = (const float*)d_in[1];
    const float* dec_w1 = (const float*)d_in[2];
    const float* dec_b1 = (const float*)d_in[3];
    const float* dec_w2 = (const float*)d_in[4];
    const float* dec_b2 = (const float*)d_in[5];
    const float* sc_w1  = (const float*)d_in[6];
    const float* sc_b1  = (const float*)d_in[7];
    const float* sc_w2  = (const float*)d_in[8];
    const float* sc_b2  = (const float*)d_in[9];
    const float* rs_w1  = (const float*)d_in[10];
    const float* rs_b1  = (const float*)d_in[11];
    const float* rs_w2  = (const float*)d_in[12];
    const float* rs_b2  = (const float*)d_in[13];

    float* ws = (float*)d_ws;
    float* out = (float*)d_out;

    prep_kernel<<<50, 256, 0, stream>>>(cb, dec_w1, sc_w1, rs_w1, ws);
    main_kernel<<<NB / 2 / 256, 256, 0, stream>>>(
        z,
        dec_b1, dec_w2, dec_b2,
        sc_b1,  sc_w2,  sc_b2,
        rs_b1,  rs_w2,  rs_b2,
        ws, ws + WS_LOSS, out);
    fin_kernel<<<1, 1, 0, stream>>>(ws, out);
}